// Round 1
// baseline (190.302 us; speedup 1.0000x reference)
//
#include <hip/hip_runtime.h>
#include <math.h>

#define OUTSZ 224
#define NBINS 8
#define NTHREADS 256
#define IMG_H 512
#define IMG_W 512

__global__ __launch_bounds__(NTHREADS) void velhist_kernel(
    const float* __restrict__ flows,  // (N,2,H,W)
    const float* __restrict__ boxes,  // (M,5)
    float* __restrict__ out)          // (M,8)
{
    const int m   = blockIdx.x;
    const int tid = threadIdx.x;

    __shared__ float s_grid[OUTSZ];
    __shared__ float s_sum[NBINS * NTHREADS];
    __shared__ float s_cnt[NBINS * NTHREADS];

    if (tid < OUTSZ) s_grid[tid] = ((float)tid + 0.5f) / (float)OUTSZ;
#pragma unroll
    for (int b = 0; b < NBINS; ++b) {
        s_sum[b * NTHREADS + tid] = 0.0f;
        s_cnt[b * NTHREADS + tid] = 0.0f;
    }

    const float bxf = boxes[m * 5 + 0];
    const float x1  = boxes[m * 5 + 1];
    const float y1  = boxes[m * 5 + 2];
    const float x2  = boxes[m * 5 + 3];
    const float y2  = boxes[m * 5 + 4];
    const int bidx  = (int)bxf;
    const float roi_w = fmaxf(x2 - x1, 1.0f);
    const float roi_h = fmaxf(y2 - y1, 1.0f);

    const size_t HW = (size_t)IMG_H * IMG_W;
    const float* __restrict__ f0 = flows + (size_t)bidx * 2 * HW;  // channel 0
    const float* __restrict__ f1 = f0 + HW;                        // channel 1
    const float Wf = (float)IMG_W, Hf = (float)IMG_H;

    // float32(pi) and float32(8/(2*pi)) exactly as numpy/jax cast them
    const float PI_F = 3.14159274101257324e+00f;
    const float KF   = (float)(8.0 / (2.0 * 3.14159265358979323846));

    __syncthreads();

    // 224*224 = 50176 = 256 * 196 exactly
    for (int s = tid; s < OUTSZ * OUTSZ; s += NTHREADS) {
        const int iy = s / OUTSZ;
        const int ix = s - iy * OUTSZ;

        const float px = x1 + s_grid[ix] * roi_w;
        const float py = y1 + s_grid[iy] * roi_h;

        const bool vx = (px >= -1.0f) && (px <= Wf);
        const bool vy = (py >= -1.0f) && (py <= Hf);

        float pcx = fminf(fmaxf(px, 0.0f), Wf - 1.0f);
        float pcy = fminf(fmaxf(py, 0.0f), Hf - 1.0f);
        const int x0 = (int)pcx;   // pcx >= 0 -> trunc == floor
        const int y0 = (int)pcy;
        const float fx = pcx - (float)x0;
        const float fy = pcy - (float)y0;
        const int x1i = min(x0 + 1, IMG_W - 1);
        const int y1i = min(y0 + 1, IMG_H - 1);

        const int r0 = y0 * IMG_W;   // W=512 -> shift
        const int r1 = y1i * IMG_W;
        const int i00 = r0 + x0, i01 = r0 + x1i;
        const int i10 = r1 + x0, i11 = r1 + x1i;

        const float wy0 = 1.0f - fy, wy1 = fy;
        const float wx0 = 1.0f - fx, wx1 = fx;
        const float w00 = wy0 * wx0, w01 = wy0 * wx1;
        const float w10 = wy1 * wx0, w11 = wy1 * wx1;

        float a = f0[i00] * w00 + f0[i01] * w01 + f0[i10] * w10 + f0[i11] * w11;
        float b = f1[i00] * w00 + f1[i01] * w01 + f1[i10] * w10 + f1[i11] * w11;

        if (!(vx && vy)) { a = 0.0f; b = 0.0f; }

        const float mag   = sqrtf(a * a + b * b);
        const float theta = atan2f(a, b);

        int bin = (int)floorf((theta + PI_F) * KF);
        bin = max(0, min(bin, NBINS - 1));

        s_sum[bin * NTHREADS + tid] += mag;
        s_cnt[bin * NTHREADS + tid] += 1.0f;
    }

    // tree-reduce 256 -> 1 per bin
    int sh = 7;
    for (int off = 128; off >= 1; off >>= 1, --sh) {
        __syncthreads();
        for (int w = tid; w < NBINS * off; w += NTHREADS) {
            const int b = w >> sh;
            const int t = w & (off - 1);
            s_sum[b * NTHREADS + t] += s_sum[b * NTHREADS + t + off];
            s_cnt[b * NTHREADS + t] += s_cnt[b * NTHREADS + t + off];
        }
    }
    __syncthreads();

    if (tid < NBINS) {
        const float ssum = s_sum[tid * NTHREADS];
        const float scnt = s_cnt[tid * NTHREADS];
        out[m * NBINS + tid] = (scnt != 0.0f) ? (ssum / fmaxf(scnt, 1.0f)) : 0.0f;
    }
}

extern "C" void kernel_launch(void* const* d_in, const int* in_sizes, int n_in,
                              void* d_out, int out_size, void* d_ws, size_t ws_size,
                              hipStream_t stream) {
    const float* flows = (const float*)d_in[0];
    const float* boxes = (const float*)d_in[1];
    float* out = (float*)d_out;
    const int M = in_sizes[1] / 5;   // 512
    velhist_kernel<<<dim3(M), dim3(NTHREADS), 0, stream>>>(flows, boxes, out);
}

// Round 2
// 125.270 us; speedup vs baseline: 1.5191x; 1.5191x over previous
//
#include <hip/hip_runtime.h>
#include <math.h>

#define OUTSZ   224
#define NBINS   8
#define NTH     256
#define IMG_H   512
#define IMG_W   512

// Histogram in LDS as float2 {sum, count} per (bin, tid): 8*256*8 = 16 KB.
// Address (bin*256+tid)*8 -> b64 access, 2-way bank aliasing (free on gfx950).

template <int CHUNKS>
__global__ __launch_bounds__(NTH) void velhist_kernel(
    const float* __restrict__ flows,   // (N,2,H,W)
    const float* __restrict__ boxes,   // (M,5)
    float* __restrict__ ws,            // partials (CHUNKS>1): [grid][16]
    float* __restrict__ out)           // (M,8)  (CHUNKS==1 path)
{
    constexpr int RPC = OUTSZ / CHUNKS;   // rows per chunk
    const int bid   = blockIdx.x;
    const int m     = (CHUNKS == 1) ? bid : (bid / CHUNKS);
    const int chunk = (CHUNKS == 1) ? 0   : (bid - m * CHUNKS);
    const int tid   = threadIdx.x;

    __shared__ float2 s_h[NBINS * NTH];   // {sum, cnt}

#pragma unroll
    for (int b = 0; b < NBINS; ++b)
        s_h[(b << 8) + tid] = make_float2(0.0f, 0.0f);

    const float bxf = boxes[m * 5 + 0];
    const float x1  = boxes[m * 5 + 1];
    const float y1  = boxes[m * 5 + 2];
    const float x2  = boxes[m * 5 + 3];
    const float y2  = boxes[m * 5 + 4];
    const int  bidx = (int)bxf;
    const float roi_w = fmaxf(x2 - x1, 1.0f);
    const float roi_h = fmaxf(y2 - y1, 1.0f);

    const size_t HW = (size_t)IMG_H * IMG_W;
    const float* __restrict__ f0 = flows + (size_t)bidx * 2 * HW;
    const float* __restrict__ f1 = f0 + HW;

    const float GINV = 1.0f / (float)OUTSZ;

    __syncthreads();

    if (tid < OUTSZ) {
        const int col = tid;
        // per-column x state (registers, computed once)
        const float gx  = ((float)col + 0.5f) * GINV;
        const float px  = x1 + gx * roi_w;
        const bool  vx  = (px >= -1.0f) && (px <= (float)IMG_W);
        const float pcx = fminf(fmaxf(px, 0.0f), (float)(IMG_W - 1));
        const int   x0  = (int)pcx;
        const float fx  = pcx - (float)x0;
        const int   x1i = min(x0 + 1, IMG_W - 1);
        const float wx0 = 1.0f - fx;

        for (int r = 0; r < RPC; ++r) {
            const int row = chunk * RPC + r;
            const float gy  = ((float)row + 0.5f) * GINV;
            const float py  = y1 + gy * roi_h;
            const bool  vy  = (py >= -1.0f) && (py <= (float)IMG_H);
            const float pcy = fminf(fmaxf(py, 0.0f), (float)(IMG_H - 1));
            const int   y0  = (int)pcy;
            const float fy  = pcy - (float)y0;
            const int   y1r = min(y0 + 1, IMG_H - 1);
            const float wy0 = 1.0f - fy;

            const int r0 = y0  << 9;   // *512
            const int r1 = y1r << 9;
            const int i00 = r0 + x0, i01 = r0 + x1i;
            const int i10 = r1 + x0, i11 = r1 + x1i;

            const float w00 = wy0 * wx0, w01 = wy0 * fx;
            const float w10 = fy  * wx0, w11 = fy  * fx;

            float a = f0[i00] * w00 + f0[i01] * w01 + f0[i10] * w10 + f0[i11] * w11;
            float b = f1[i00] * w00 + f1[i01] * w01 + f1[i10] * w10 + f1[i11] * w11;

            const bool valid = vx && vy;
            if (!valid) { a = 0.0f; b = 0.0f; }

            const float mag = sqrtf(a * a + b * b);

            // octant of atan2(a, b), Gray-decoded from 3 sign/compare bits
            const int p = (a >= 0.0f) ? 1 : 0;
            const int q = (b >= 0.0f) ? 1 : 0;
            const int t = (fabsf(a) >= fabsf(b)) ? 1 : 0;
            const int u = p ^ q;
            int bin = (p << 2) | (u << 1) | (u ^ t);
            if (!valid) bin = 4;   // atan2(0,0)=0 -> bin 4

            const int hidx = (bin << 8) + tid;
            float2 h = s_h[hidx];
            h.x += mag;
            h.y += 1.0f;
            s_h[hidx] = h;
        }
    }

    // tree-reduce 256 -> 1 per bin
    int sh = 7;
    for (int off = 128; off >= 1; off >>= 1, --sh) {
        __syncthreads();
        for (int w = tid; w < NBINS * off; w += NTH) {
            const int b = w >> sh;
            const int t = w & (off - 1);
            float2 lo = s_h[(b << 8) + t];
            float2 hi = s_h[(b << 8) + t + off];
            lo.x += hi.x; lo.y += hi.y;
            s_h[(b << 8) + t] = lo;
        }
    }
    __syncthreads();

    if (tid < NBINS) {
        const float2 h = s_h[tid << 8];
        if (CHUNKS == 1) {
            out[m * NBINS + tid] = (h.y != 0.0f) ? (h.x / fmaxf(h.y, 1.0f)) : 0.0f;
        } else {
            float* p = ws + bid * 16;
            p[tid]     = h.x;
            p[tid + 8] = h.y;
        }
    }
}

__global__ __launch_bounds__(NTH) void finalize_kernel(
    const float* __restrict__ ws, float* __restrict__ out, int M, int chunks)
{
    const int i = blockIdx.x * NTH + threadIdx.x;
    if (i >= M * NBINS) return;
    const int m = i >> 3;
    const int b = i & 7;
    float s = 0.0f, c = 0.0f;
    for (int ch = 0; ch < chunks; ++ch) {
        const float* p = ws + (size_t)(m * chunks + ch) * 16;
        s += p[b];
        c += p[b + 8];
    }
    out[i] = (c != 0.0f) ? (s / fmaxf(c, 1.0f)) : 0.0f;
}

extern "C" void kernel_launch(void* const* d_in, const int* in_sizes, int n_in,
                              void* d_out, int out_size, void* d_ws, size_t ws_size,
                              hipStream_t stream) {
    const float* flows = (const float*)d_in[0];
    const float* boxes = (const float*)d_in[1];
    float* out = (float*)d_out;
    const int M = in_sizes[1] / 5;   // 512

    const int CH = 4;
    const size_t need = (size_t)M * CH * 16 * sizeof(float);   // 128 KB for M=512
    if (ws_size >= need) {
        velhist_kernel<4><<<dim3(M * CH), dim3(NTH), 0, stream>>>(
            flows, boxes, (float*)d_ws, nullptr);
        finalize_kernel<<<dim3((M * NBINS + NTH - 1) / NTH), dim3(NTH), 0, stream>>>(
            (const float*)d_ws, out, M, CH);
    } else {
        velhist_kernel<1><<<dim3(M), dim3(NTH), 0, stream>>>(
            flows, boxes, nullptr, out);
    }
}